// Round 7
// baseline (827.794 us; speedup 1.0000x reference)
//
#include <hip/hip_runtime.h>
#include <hip/hip_bf16.h>

// MultiHeadedAttention: B=4, T=2048, F=1024, h=16, dk=64.
// f32->bf16 converts -> 3 proj GEMMs (Q pre-scaled, V transposed)
// -> flash attn v6 (2 Q-sets/wave + in-block split-K, 8 waves) -> out GEMM.

typedef unsigned short u16;
typedef unsigned long long u64;
typedef __attribute__((ext_vector_type(8))) short short8;
typedef __attribute__((ext_vector_type(4))) float f32x4;
typedef __attribute__((ext_vector_type(16))) float f32x16;
typedef __attribute__((ext_vector_type(4))) unsigned int u32x4;

#define GLOAD16(g, l) __builtin_amdgcn_global_load_lds( \
    (const __attribute__((address_space(1))) unsigned int*)(g), \
    (__attribute__((address_space(3))) unsigned int*)(l), 16, 0, 0)

__device__ __forceinline__ u16 f2bf(float x) {
  unsigned int u = __float_as_uint(x);
  return (u16)((u + 0x7fffu + ((u >> 16) & 1u)) >> 16);  // RNE, finite inputs
}

__device__ __forceinline__ float fexp2(float x) {
#if __has_builtin(__builtin_amdgcn_exp2f)
  return __builtin_amdgcn_exp2f(x);
#else
  return exp2f(x);
#endif
}

__device__ __forceinline__ unsigned cvtpk(float lo, float hi) {
  unsigned r;
  asm("v_cvt_pk_bf16_f32 %0, %1, %2" : "=v"(r) : "v"(lo), "v"(hi));
  return r;
}

// ---------------- f32 -> bf16 multi-tensor convert ----------------
struct CvtArgs {
  const float* src[4];
  u16* dst[4];
};

__global__ __launch_bounds__(256) void cvt_multi(CvtArgs a, int shift) {
  const int id = blockIdx.x * 256 + threadIdx.x;
  const int seg = id >> shift;
  const int off = id & ((1 << shift) - 1);
  float4 v = ((const float4*)a.src[seg])[off];
  ushort4 o;
  o.x = f2bf(v.x); o.y = f2bf(v.y); o.z = f2bf(v.z); o.w = f2bf(v.w);
  ((ushort4*)a.dst[seg])[off] = o;
}

// ---------------- GEMM: C[M,N] = A[M,K] * B[N,K]^T + bias ----------------
template <int EPI>
__global__ __launch_bounds__(256) void gemm_bt(const u16* __restrict__ A,
                                               const u16* __restrict__ Bw,
                                               const float* __restrict__ bias,
                                               void* __restrict__ Cout,
                                               float scale) {
  __shared__ u16 As[128 * 64];
  __shared__ u16 Bs[128 * 64];
  const int t = threadIdx.x;
  const int lane = t & 63;
  const int w = t >> 6;
  const int wm = w >> 1, wn = w & 1;
  const int l15 = lane & 15, l4 = lane >> 4;

  const int bid = blockIdx.x;
  const int swz = (bid & 7) * 64 + (bid >> 3);
  const int brow = swz >> 3;  // 64 M-tiles
  const int bcol = swz & 7;   // 8 N-tiles

  f32x4 acc[4][4] = {};

  const int srow = t >> 3;          // 0..31
  const int sbyte = (t & 7) * 16;   // 0..112

  for (int kt = 0; kt < 16; ++kt) {
    const int k0 = kt * 64;
    __syncthreads();
#pragma unroll
    for (int i = 0; i < 4; ++i) {
      const int r = i * 32 + srow;
      const int sb = sbyte ^ ((r & 7) << 4);
      GLOAD16((const char*)(A + (size_t)(brow * 128 + r) * 1024 + k0) + sb,
              &As[(i * 4096 + t * 16) >> 1]);
      GLOAD16((const char*)(Bw + (size_t)(bcol * 128 + r) * 1024 + k0) + sb,
              &Bs[(i * 4096 + t * 16) >> 1]);
    }
    __syncthreads();
#pragma unroll
    for (int kf = 0; kf < 2; ++kf) {
      short8 af[4], bfv[4];
#pragma unroll
      for (int mi = 0; mi < 4; ++mi) {
        const int r = wm * 64 + mi * 16 + l15;
        const int byt = r * 128 + ((kf * 64 + l4 * 16) ^ ((r & 7) << 4));
        af[mi] = *(const short8*)&As[byt >> 1];
      }
#pragma unroll
      for (int ni = 0; ni < 4; ++ni) {
        const int r = wn * 64 + ni * 16 + l15;
        const int byt = r * 128 + ((kf * 64 + l4 * 16) ^ ((r & 7) << 4));
        bfv[ni] = *(const short8*)&Bs[byt >> 1];
      }
#pragma unroll
      for (int mi = 0; mi < 4; ++mi)
#pragma unroll
        for (int ni = 0; ni < 4; ++ni)
          acc[mi][ni] = __builtin_amdgcn_mfma_f32_16x16x32_bf16(
              af[mi], bfv[ni], acc[mi][ni], 0, 0, 0);
    }
  }

#pragma unroll
  for (int ni = 0; ni < 4; ++ni) {
    const int n = bcol * 128 + wn * 64 + ni * 16 + l15;
    const float bn = bias[n];
#pragma unroll
    for (int mi = 0; mi < 4; ++mi) {
      const int mb = brow * 128 + wm * 64 + mi * 16 + l4 * 4;
#pragma unroll
      for (int r = 0; r < 4; ++r) {
        const float v = acc[mi][ni][r] + bn;
        const int m = mb + r;
        const int b_ = m >> 11, tok = m & 2047, h_ = n >> 6, d = n & 63;
        if (EPI == 0) {
          ((u16*)Cout)[(((size_t)(b_ * 16 + h_) * 2048 + tok) << 6) + d] = f2bf(v * scale);
        } else if (EPI == 2) {
          ((u16*)Cout)[(((size_t)(b_ * 16 + h_) * 64 + d) << 11) + tok] = f2bf(v);
        } else {
          ((float*)Cout)[(size_t)m * 1024 + n] = v;
        }
      }
    }
  }
}

// ---------------- Flash attention v6: 2 Q-sets/wave + in-block split-K ----------------
// Grid: 64 heads * 8 q-tiles = 512 blocks, 512 threads (8 waves).
// Wave w: q-subtile (w&3) [64 queries, 2 Q-sets], key-half (w>>2) [1024 keys, 16 tiles].
// Fixed-max softmax => split-K partials combine additively: O=O0+O1, l=l0+l1 (via LDS).
__global__ __launch_bounds__(512, 4) void attn_fwd6(const u16* __restrict__ Q,
                                                    const u16* __restrict__ Kp,
                                                    const u16* __restrict__ Vt,
                                                    const int* __restrict__ mask,
                                                    u16* __restrict__ ctx) {
  // 64 KB: K tiles [khalf][dbuf] 32KB, V tiles 32KB; epilogue overlays combine buffer.
  __shared__ __align__(16) char smem[65536];

  const int t = threadIdx.x, lane = t & 63, w = t >> 6;
  const int q31 = lane & 31, hi = lane >> 5;
  const int khalf = w >> 2;            // 0/1: key range
  const int koff = khalf << 10;        // 0 or 1024

  const int bid = blockIdx.x;          // 512 blocks, 512%8==0
  const int swz = (bid & 7) * 64 + (bid >> 3);
  const int bh = swz >> 3;             // 0..63
  const int b_ = bh >> 4, h_ = bh & 15;
  const int q0 = (swz & 7) * 256 + (w & 3) * 64;  // wave owns 64 queries
  const size_t headO = (size_t)bh * 131072;       // 2048*64

  // Q B-fragments for both sets (col = query, k-slice = hi*8+j)
  short8 qfA[4], qfB[4];
  {
    const u16* qrowA = Q + headO + (size_t)(q0 + q31) * 64 + hi * 8;
    const u16* qrowB = qrowA + 32 * 64;
#pragma unroll
    for (int ds = 0; ds < 4; ++ds) {
      qfA[ds] = *(const short8*)(qrowA + ds * 16);
      qfB[ds] = *(const short8*)(qrowB + ds * 16);
    }
  }

  // staging: each khalf-group (4 waves = 256 threads) stages its own K/V tile
  const int tl = t & 255;
  const int srow = tl >> 3;          // 0..31
  const int sbyte = (tl & 7) * 16;   // 0..112

#define STAGE_KV(bufi, kb)                                                        \
  {                                                                               \
    char* kdst = smem + (khalf << 14) + ((bufi) << 13) + tl * 16;                 \
    char* vdst = smem + 32768 + (khalf << 14) + ((bufi) << 13) + tl * 16;         \
    _Pragma("unroll") for (int i = 0; i < 2; ++i) {                               \
      const int r = i * 32 + srow;                                                \
      const int sb = sbyte ^ ((r & 7) << 4);                                      \
      GLOAD16((const char*)(Kp + headO + (size_t)(koff + (kb) + r) * 64) + sb,    \
              (u16*)(kdst + i * 4096));                                           \
      GLOAD16((const char*)(Vt + headO + (size_t)r * 2048 + koff + (kb)) + sb,    \
              (u16*)(vdst + i * 4096));                                           \
    }                                                                             \
  }

#define PACK(sv, pfa, pfb)                                                      \
  {                                                                             \
    const unsigned w0 = cvtpk(sv[0], sv[1]),   w1 = cvtpk(sv[2], sv[3]);        \
    const unsigned w2 = cvtpk(sv[4], sv[5]),   w3 = cvtpk(sv[6], sv[7]);        \
    const unsigned w4 = cvtpk(sv[8], sv[9]),   w5 = cvtpk(sv[10], sv[11]);      \
    const unsigned w6 = cvtpk(sv[12], sv[13]), w7 = cvtpk(sv[14], sv[15]);      \
    const unsigned x0 = (unsigned)__shfl_xor((int)(hi ? w0 : w2), 32);          \
    const unsigned x1 = (unsigned)__shfl_xor((int)(hi ? w1 : w3), 32);          \
    const unsigned y0 = (unsigned)__shfl_xor((int)(hi ? w4 : w6), 32);          \
    const unsigned y1 = (unsigned)__shfl_xor((int)(hi ? w5 : w7), 32);          \
    u32x4 fa = hi ? (u32x4){x0, x1, w2, w3} : (u32x4){w0, w1, x0, x1};          \
    u32x4 fb = hi ? (u32x4){y0, y1, w6, w7} : (u32x4){w4, w5, y0, y1};          \
    pfa = __builtin_bit_cast(short8, fa);                                       \
    pfb = __builtin_bit_cast(short8, fb);                                       \
  }

  f32x16 oA0 = {}, oA1 = {}, oB0 = {}, oB1 = {};
  float lA = 0.f, lB = 0.f;
  const int kcol = hi * 16;
  const int rswz = (q31 & 7) << 4;

  STAGE_KV(0, 0);
  int mk = mask[b_ * 2048 + koff + lane];
  __syncthreads();

  int buf = 0;
  for (int kt = 0; kt < 16; ++kt) {
    const int kb = kt * 64;
    if (kt + 1 < 16) STAGE_KV(buf ^ 1, kb + 64);
    const int mk_next = (kt + 1 < 16) ? mask[b_ * 2048 + koff + kb + 64 + lane] : 0;
    const u64 bits = __ballot(mk != 0);

    const char* kc = smem + (khalf << 14) + (buf << 13);
    const char* vc = kc + 32768;

#pragma unroll
    for (int half = 0; half < 2; ++half) {
      // S^T = K * Q for this 32-key half; each ka feeds BOTH Q-sets
      f32x16 sA = {}, sB = {};
      __builtin_amdgcn_s_setprio(1);
#pragma unroll
      for (int ds = 0; ds < 4; ++ds) {
        const int byt = (half * 32 + q31) * 128 + ((ds * 32 + kcol) ^ rswz);
        short8 ka = *(const short8*)(kc + byt);
        sA = __builtin_amdgcn_mfma_f32_32x32x16_bf16(ka, qfA[ds], sA, 0, 0, 0);
        sB = __builtin_amdgcn_mfma_f32_32x32x16_bf16(ka, qfB[ds], sB, 0, 0, 0);
      }
      __builtin_amdgcn_s_setprio(0);

      // p = exp2(s) in place (fixed max; Q pre-scaled to base-2 units)
      if (bits == ~0ull) {
#pragma unroll
        for (int r = 0; r < 16; ++r) { sA[r] = fexp2(sA[r]); sB[r] = fexp2(sB[r]); }
      } else {
#pragma unroll
        for (int r = 0; r < 16; ++r) {
          const int k0 = half * 32 + (r & 3) + 8 * (r >> 2) + 4 * hi;
          const bool on = (bits >> k0) & 1;
          sA[r] = on ? fexp2(sA[r]) : 0.f;
          sB[r] = on ? fexp2(sB[r]) : 0.f;
        }
      }

      // lane-local partial sums
      {
        float a0 = 0.f, a1 = 0.f, b0 = 0.f, b1 = 0.f;
#pragma unroll
        for (int r = 0; r < 16; r += 2) {
          a0 += sA[r]; a1 += sA[r + 1];
          b0 += sB[r]; b1 += sB[r + 1];
        }
        lA += a0 + a1;
        lB += b0 + b1;
      }

      short8 pA0, pA1, pB0, pB1;
      PACK(sA, pA0, pA1);
      PACK(sB, pB0, pB1);

      // O^T += V^T * P^T; each va feeds BOTH Q-sets
      __builtin_amdgcn_s_setprio(1);
      {
        const int rb0 = q31 * 128, rb1 = (32 + q31) * 128;
        const int c0 = (half * 64 + kcol) ^ rswz;
        const int c1 = (half * 64 + 32 + kcol) ^ rswz;
        short8 va;
        va = *(const short8*)(vc + rb0 + c0);
        oA0 = __builtin_amdgcn_mfma_f32_32x32x16_bf16(va, pA0, oA0, 0, 0, 0);
        oB0 = __builtin_amdgcn_mfma_f32_32x32x16_bf16(va, pB0, oB0, 0, 0, 0);
        va = *(const short8*)(vc + rb0 + c1);
        oA0 = __builtin_amdgcn_mfma_f32_32x32x16_bf16(va, pA1, oA0, 0, 0, 0);
        oB0 = __builtin_amdgcn_mfma_f32_32x32x16_bf16(va, pB1, oB0, 0, 0, 0);
        va = *(const short8*)(vc + rb1 + c0);
        oA1 = __builtin_amdgcn_mfma_f32_32x32x16_bf16(va, pA0, oA1, 0, 0, 0);
        oB1 = __builtin_amdgcn_mfma_f32_32x32x16_bf16(va, pB0, oB1, 0, 0, 0);
        va = *(const short8*)(vc + rb1 + c1);
        oA1 = __builtin_amdgcn_mfma_f32_32x32x16_bf16(va, pA1, oA1, 0, 0, 0);
        oB1 = __builtin_amdgcn_mfma_f32_32x32x16_bf16(va, pB1, oB1, 0, 0, 0);
      }
      __builtin_amdgcn_s_setprio(0);
    }

    mk = mk_next;
    __syncthreads();
    buf ^= 1;
  }
#undef STAGE_KV

  // ---- split-K combine: pairs (0,4),(1,5) round 0; (2,6),(3,7) round 1 ----
  // Waves 4-7 write partials (16 f32x4 + 2 f32) to LDS; waves 0-3 accumulate.
  float* comb = (float*)smem;  // overlays K/V (dead after final barrier above)
#pragma unroll
  for (int rnd = 0; rnd < 2; ++rnd) {
    if ((w >> 1) == 2 + rnd) {
      float* dst = comb + ((w & 1) * 64 + lane) * 68;
      float4* d4 = (float4*)dst;
#pragma unroll
      for (int g = 0; g < 4; ++g) {
        d4[g]      = make_float4(oA0[4*g], oA0[4*g+1], oA0[4*g+2], oA0[4*g+3]);
        d4[4 + g]  = make_float4(oA1[4*g], oA1[4*g+1], oA1[4*g+2], oA1[4*g+3]);
        d4[8 + g]  = make_float4(oB0[4*g], oB0[4*g+1], oB0[4*g+2], oB0[4*g+3]);
        d4[12 + g] = make_float4(oB1[4*g], oB1[4*g+1], oB1[4*g+2], oB1[4*g+3]);
      }
      dst[64] = lA; dst[65] = lB;
    }
    __syncthreads();
    if ((w >> 1) == rnd) {
      const float* src = comb + ((w & 1) * 64 + lane) * 68;
      const float4* s4 = (const float4*)src;
#pragma unroll
      for (int g = 0; g < 4; ++g) {
        float4 x;
        x = s4[g];      oA0[4*g] += x.x; oA0[4*g+1] += x.y; oA0[4*g+2] += x.z; oA0[4*g+3] += x.w;
        x = s4[4 + g];  oA1[4*g] += x.x; oA1[4*g+1] += x.y; oA1[4*g+2] += x.z; oA1[4*g+3] += x.w;
        x = s4[8 + g];  oB0[4*g] += x.x; oB0[4*g+1] += x.y; oB0[4*g+2] += x.z; oB0[4*g+3] += x.w;
        x = s4[12 + g]; oB1[4*g] += x.x; oB1[4*g+1] += x.y; oB1[4*g+2] += x.z; oB1[4*g+3] += x.w;
      }
      lA += src[64]; lB += src[65];
    }
    __syncthreads();
  }

  if (w < 4) {
    // finish l sums (cross-half shfl), normalize, store
    lA += __shfl_xor(lA, 32);
    lB += __shfl_xor(lB, 32);
    const float invA = lA > 0.f ? 1.f / lA : 0.f;
    const float invB = lB > 0.f ? 1.f / lB : 0.f;
    const int tokA = q0 + q31;
    u16* crowA = ctx + ((size_t)b_ * 2048 + tokA) * 1024 + h_ * 64 + 4 * hi;
    u16* crowB = crowA + 32 * 1024;
#pragma unroll
    for (int g = 0; g < 4; ++g) {
      unsigned u0, u1;
      u0 = cvtpk(oA0[4 * g + 0] * invA, oA0[4 * g + 1] * invA);
      u1 = cvtpk(oA0[4 * g + 2] * invA, oA0[4 * g + 3] * invA);
      *(uint2*)(crowA + 8 * g) = make_uint2(u0, u1);
      u0 = cvtpk(oA1[4 * g + 0] * invA, oA1[4 * g + 1] * invA);
      u1 = cvtpk(oA1[4 * g + 2] * invA, oA1[4 * g + 3] * invA);
      *(uint2*)(crowA + 32 + 8 * g) = make_uint2(u0, u1);
      u0 = cvtpk(oB0[4 * g + 0] * invB, oB0[4 * g + 1] * invB);
      u1 = cvtpk(oB0[4 * g + 2] * invB, oB0[4 * g + 3] * invB);
      *(uint2*)(crowB + 8 * g) = make_uint2(u0, u1);
      u0 = cvtpk(oB1[4 * g + 0] * invB, oB1[4 * g + 1] * invB);
      u1 = cvtpk(oB1[4 * g + 2] * invB, oB1[4 * g + 3] * invB);
      *(uint2*)(crowB + 32 + 8 * g) = make_uint2(u0, u1);
    }
  }
}

// ---------------- host launcher ----------------
extern "C" void kernel_launch(void* const* d_in, const int* in_sizes, int n_in,
                              void* d_out, int out_size, void* d_ws, size_t ws_size,
                              hipStream_t stream) {
  const float* q_in = (const float*)d_in[0];
  const float* k_in = (const float*)d_in[1];
  const float* v_in = (const float*)d_in[2];
  const int*   mask = (const int*)d_in[3];
  const float* Wq = (const float*)d_in[4];
  const float* bq = (const float*)d_in[5];
  const float* Wk = (const float*)d_in[6];
  const float* bk = (const float*)d_in[7];
  const float* Wv = (const float*)d_in[8];
  const float* bv = (const float*)d_in[9];
  const float* Wo = (const float*)d_in[10];
  const float* bo = (const float*)d_in[11];
  float* out = (float*)d_out;

  char* ws = (char*)d_ws;
  u16* xq = (u16*)(ws);                        // bf16 query  [B,T,F]
  u16* xk = (u16*)(ws + 16777216);             // bf16 key
  u16* xv = (u16*)(ws + 33554432);             // bf16 value
  u16* Qp = (u16*)(ws + 50331648);             // [B,h,T,dk], pre-scaled
  u16* Kp = (u16*)(ws + 67108864);             // [B,h,T,dk]
  u16* Vtb = (u16*)(ws + 83886080);            // [B,h,dk,T]
  u16* wqb = (u16*)(ws + 100663296);           // bf16 weights, 2 MiB each
  u16* wkb = (u16*)(ws + 102760448);
  u16* wvb = (u16*)(ws + 104857600);
  u16* wob = (u16*)(ws + 106954752);
  u16* ctx = xk;  // [B,T,F] (key bf16 dead after K projection)

  // converts: 3 big tensors (2^21 float4 each), 4 weights (2^18 float4 each)
  CvtArgs big;
  big.src[0] = q_in; big.src[1] = k_in; big.src[2] = v_in; big.src[3] = v_in;
  big.dst[0] = xq;   big.dst[1] = xk;   big.dst[2] = xv;   big.dst[3] = xv;
  cvt_multi<<<3 * 8192, 256, 0, stream>>>(big, 21);
  CvtArgs wts;
  wts.src[0] = Wq;  wts.src[1] = Wk;  wts.src[2] = Wv;  wts.src[3] = Wo;
  wts.dst[0] = wqb; wts.dst[1] = wkb; wts.dst[2] = wvb; wts.dst[3] = wob;
  cvt_multi<<<4 * 1024, 256, 0, stream>>>(wts, 18);

  const float C_SCALE = 0.18033688011112042f;  // (1/sqrt(64)) * log2(e)
  gemm_bt<0><<<512, 256, 0, stream>>>(xq, wqb, bq, Qp, C_SCALE);
  gemm_bt<0><<<512, 256, 0, stream>>>(xk, wkb, bk, Kp, 1.0f);
  gemm_bt<2><<<512, 256, 0, stream>>>(xv, wvb, bv, Vtb, 1.0f);

  attn_fwd6<<<512, 512, 0, stream>>>(Qp, Kp, Vtb, mask, ctx);

  gemm_bt<1><<<512, 256, 0, stream>>>(ctx, wob, bo, out, 1.0f);
}

// Round 8
// 240.171 us; speedup vs baseline: 3.4467x; 3.4467x over previous
//
#include <hip/hip_runtime.h>
#include <hip/hip_bf16.h>

// MultiHeadedAttention: B=4, T=2048, F=1024, h=16, dk=64.
// f32->bf16 converts -> 3 proj GEMMs (Q pre-scaled, V transposed)
// -> flash attn v7 (2 Q-sets/wave, reg-staged K/V, raw-barrier pipeline) -> out GEMM.

typedef unsigned short u16;
typedef unsigned long long u64;
typedef __attribute__((ext_vector_type(8))) short short8;
typedef __attribute__((ext_vector_type(4))) float f32x4;
typedef __attribute__((ext_vector_type(16))) float f32x16;
typedef __attribute__((ext_vector_type(4))) unsigned int u32x4;

#define GLOAD16(g, l) __builtin_amdgcn_global_load_lds( \
    (const __attribute__((address_space(1))) unsigned int*)(g), \
    (__attribute__((address_space(3))) unsigned int*)(l), 16, 0, 0)

__device__ __forceinline__ u16 f2bf(float x) {
  unsigned int u = __float_as_uint(x);
  return (u16)((u + 0x7fffu + ((u >> 16) & 1u)) >> 16);  // RNE, finite inputs
}

__device__ __forceinline__ float fexp2(float x) {
#if __has_builtin(__builtin_amdgcn_exp2f)
  return __builtin_amdgcn_exp2f(x);
#else
  return exp2f(x);
#endif
}

__device__ __forceinline__ unsigned cvtpk(float lo, float hi) {
  unsigned r;
  asm("v_cvt_pk_bf16_f32 %0, %1, %2" : "=v"(r) : "v"(lo), "v"(hi));
  return r;
}

// ---------------- f32 -> bf16 multi-tensor convert ----------------
struct CvtArgs {
  const float* src[4];
  u16* dst[4];
};

__global__ __launch_bounds__(256) void cvt_multi(CvtArgs a, int shift) {
  const int id = blockIdx.x * 256 + threadIdx.x;
  const int seg = id >> shift;
  const int off = id & ((1 << shift) - 1);
  float4 v = ((const float4*)a.src[seg])[off];
  ushort4 o;
  o.x = f2bf(v.x); o.y = f2bf(v.y); o.z = f2bf(v.z); o.w = f2bf(v.w);
  ((ushort4*)a.dst[seg])[off] = o;
}

// ---------------- GEMM: C[M,N] = A[M,K] * B[N,K]^T + bias ----------------
template <int EPI>
__global__ __launch_bounds__(256) void gemm_bt(const u16* __restrict__ A,
                                               const u16* __restrict__ Bw,
                                               const float* __restrict__ bias,
                                               void* __restrict__ Cout,
                                               float scale) {
  __shared__ u16 As[128 * 64];
  __shared__ u16 Bs[128 * 64];
  const int t = threadIdx.x;
  const int lane = t & 63;
  const int w = t >> 6;
  const int wm = w >> 1, wn = w & 1;
  const int l15 = lane & 15, l4 = lane >> 4;

  const int bid = blockIdx.x;
  const int swz = (bid & 7) * 64 + (bid >> 3);
  const int brow = swz >> 3;  // 64 M-tiles
  const int bcol = swz & 7;   // 8 N-tiles

  f32x4 acc[4][4] = {};

  const int srow = t >> 3;          // 0..31
  const int sbyte = (t & 7) * 16;   // 0..112

  for (int kt = 0; kt < 16; ++kt) {
    const int k0 = kt * 64;
    __syncthreads();
#pragma unroll
    for (int i = 0; i < 4; ++i) {
      const int r = i * 32 + srow;
      const int sb = sbyte ^ ((r & 7) << 4);
      GLOAD16((const char*)(A + (size_t)(brow * 128 + r) * 1024 + k0) + sb,
              &As[(i * 4096 + t * 16) >> 1]);
      GLOAD16((const char*)(Bw + (size_t)(bcol * 128 + r) * 1024 + k0) + sb,
              &Bs[(i * 4096 + t * 16) >> 1]);
    }
    __syncthreads();
#pragma unroll
    for (int kf = 0; kf < 2; ++kf) {
      short8 af[4], bfv[4];
#pragma unroll
      for (int mi = 0; mi < 4; ++mi) {
        const int r = wm * 64 + mi * 16 + l15;
        const int byt = r * 128 + ((kf * 64 + l4 * 16) ^ ((r & 7) << 4));
        af[mi] = *(const short8*)&As[byt >> 1];
      }
#pragma unroll
      for (int ni = 0; ni < 4; ++ni) {
        const int r = wn * 64 + ni * 16 + l15;
        const int byt = r * 128 + ((kf * 64 + l4 * 16) ^ ((r & 7) << 4));
        bfv[ni] = *(const short8*)&Bs[byt >> 1];
      }
#pragma unroll
      for (int mi = 0; mi < 4; ++mi)
#pragma unroll
        for (int ni = 0; ni < 4; ++ni)
          acc[mi][ni] = __builtin_amdgcn_mfma_f32_16x16x32_bf16(
              af[mi], bfv[ni], acc[mi][ni], 0, 0, 0);
    }
  }

#pragma unroll
  for (int ni = 0; ni < 4; ++ni) {
    const int n = bcol * 128 + wn * 64 + ni * 16 + l15;
    const float bn = bias[n];
#pragma unroll
    for (int mi = 0; mi < 4; ++mi) {
      const int mb = brow * 128 + wm * 64 + mi * 16 + l4 * 4;
#pragma unroll
      for (int r = 0; r < 4; ++r) {
        const float v = acc[mi][ni][r] + bn;
        const int m = mb + r;
        const int b_ = m >> 11, tok = m & 2047, h_ = n >> 6, d = n & 63;
        if (EPI == 0) {
          ((u16*)Cout)[(((size_t)(b_ * 16 + h_) * 2048 + tok) << 6) + d] = f2bf(v * scale);
        } else if (EPI == 2) {
          ((u16*)Cout)[(((size_t)(b_ * 16 + h_) * 64 + d) << 11) + tok] = f2bf(v);
        } else {
          ((float*)Cout)[(size_t)m * 1024 + n] = v;
        }
      }
    }
  }
}

// ---------------- Flash attention v7: reg-staged K/V + raw-barrier pipeline ----------------
// Grid: 64 heads * 8 q-tiles = 512 blocks, 256 threads (4 waves x 64 Q-rows, 2 Q-sets).
// Per tile: ds_write(regs of tile k) -> issue loads(tile k+1) -> lgkmcnt(0) -> s_barrier
//           -> compute -> s_barrier.  Loads stay in flight across barriers (no vmcnt drain).
__global__ __launch_bounds__(256, 2) void attn_fwd7(const u16* __restrict__ Q,
                                                    const u16* __restrict__ Kp,
                                                    const u16* __restrict__ Vt,
                                                    const int* __restrict__ mask,
                                                    u16* __restrict__ ctx) {
  __shared__ u16 Ks[64 * 64];  // 8 KB
  __shared__ u16 Vs[64 * 64];  // 8 KB

  const int t = threadIdx.x, lane = t & 63, w = t >> 6;
  const int q31 = lane & 31, hi = lane >> 5;

  const int bid = blockIdx.x;                 // 512 blocks, 512%8==0
  const int swz = (bid & 7) * 64 + (bid >> 3);
  const int bh = swz >> 3;                    // 0..63
  const int b_ = bh >> 4, h_ = bh & 15;
  const int q0 = (swz & 7) * 256 + w * 64;    // wave owns 64 queries
  const size_t headO = (size_t)bh * 131072;   // 2048*64

  // Q B-fragments for both sets (col = query, k-slice = hi*8+j)
  short8 qfA[4], qfB[4];
  {
    const u16* qrowA = Q + headO + (size_t)(q0 + q31) * 64 + hi * 8;
    const u16* qrowB = qrowA + 32 * 64;
#pragma unroll
    for (int ds = 0; ds < 4; ++ds) {
      qfA[ds] = *(const short8*)(qrowA + ds * 16);
      qfB[ds] = *(const short8*)(qrowB + ds * 16);
    }
  }

  // staging geometry: 256 lanes x 2 chunks x 16B each for K and V (8 KB tiles)
  const int srow = t >> 3;          // 0..31
  const int sbyte = (t & 7) * 16;   // 0..112
  int lofs[2];                      // swizzled LDS byte offset (same for K and V)
#pragma unroll
  for (int i = 0; i < 2; ++i) {
    const int r = i * 32 + srow;
    lofs[i] = r * 128 + (sbyte ^ ((r & 7) << 4));
  }
  // linear global base addresses
  const char* kgb = (const char*)(Kp + headO) + (size_t)srow * 128 + sbyte;   // + kb*128 + i*4096
  const char* vgb = (const char*)(Vt + headO) + (size_t)srow * 4096 + sbyte;  // + kb*2 + i*131072

  uint4 kr[2], vr[2];
#define LOADT(kb)                                                   \
  {                                                                 \
    kr[0] = *(const uint4*)(kgb + (size_t)(kb) * 128);              \
    kr[1] = *(const uint4*)(kgb + (size_t)(kb) * 128 + 4096);       \
    vr[0] = *(const uint4*)(vgb + (size_t)(kb) * 2);                \
    vr[1] = *(const uint4*)(vgb + (size_t)(kb) * 2 + 131072);       \
  }

#define PACK(sv, pfa, pfb)                                                      \
  {                                                                             \
    const unsigned w0 = cvtpk(sv[0], sv[1]),   w1 = cvtpk(sv[2], sv[3]);        \
    const unsigned w2 = cvtpk(sv[4], sv[5]),   w3 = cvtpk(sv[6], sv[7]);        \
    const unsigned w4 = cvtpk(sv[8], sv[9]),   w5 = cvtpk(sv[10], sv[11]);      \
    const unsigned w6 = cvtpk(sv[12], sv[13]), w7 = cvtpk(sv[14], sv[15]);      \
    const unsigned x0 = (unsigned)__shfl_xor((int)(hi ? w0 : w2), 32);          \
    const unsigned x1 = (unsigned)__shfl_xor((int)(hi ? w1 : w3), 32);          \
    const unsigned y0 = (unsigned)__shfl_xor((int)(hi ? w4 : w6), 32);          \
    const unsigned y1 = (unsigned)__shfl_xor((int)(hi ? w5 : w7), 32);          \
    u32x4 fa = hi ? (u32x4){x0, x1, w2, w3} : (u32x4){w0, w1, x0, x1};          \
    u32x4 fb = hi ? (u32x4){y0, y1, w6, w7} : (u32x4){w4, w5, y0, y1};          \
    pfa = __builtin_bit_cast(short8, fa);                                       \
    pfb = __builtin_bit_cast(short8, fb);                                       \
  }

  f32x16 oA0 = {}, oA1 = {}, oB0 = {}, oB1 = {};
  float lA = 0.f, lB = 0.f;
  const int kcol = hi * 16;
  const int rswz = (q31 & 7) << 4;

  // prologue: tile-0 mask + tile-0 loads in flight
  int mk = mask[b_ * 2048 + lane];
  LOADT(0);
  int mk_next;

  for (int kt = 0; kt < 32; ++kt) {
    const int kb = kt * 64;

    // ds_write tile kt (compiler inserts the vmcnt wait for kr/vr readiness)
    *(uint4*)((char*)Ks + lofs[0]) = kr[0];
    *(uint4*)((char*)Ks + lofs[1]) = kr[1];
    *(uint4*)((char*)Vs + lofs[0]) = vr[0];
    *(uint4*)((char*)Vs + lofs[1]) = vr[1];

    // issue next-tile loads (mask first so its wait never drains tile loads)
    if (kt < 31) {
      mk_next = mask[b_ * 2048 + kb + 64 + lane];
      LOADT(kb + 64);
    } else {
      mk_next = 0;
    }

    asm volatile("s_waitcnt lgkmcnt(0)" ::: "memory");  // ds_writes landed
    __builtin_amdgcn_sched_barrier(0);
    __builtin_amdgcn_s_barrier();                        // raw: vmcnt rides across
    __builtin_amdgcn_sched_barrier(0);

    const u64 bits = __ballot(mk != 0);

#pragma unroll
    for (int half = 0; half < 2; ++half) {
      // S^T = K * Q for this 32-key half; each ka feeds BOTH Q-sets
      f32x16 sA = {}, sB = {};
      __builtin_amdgcn_s_setprio(1);
#pragma unroll
      for (int ds = 0; ds < 4; ++ds) {
        const int byt = (half * 32 + q31) * 128 + ((ds * 32 + kcol) ^ rswz);
        short8 ka = *(const short8*)((const char*)Ks + byt);
        sA = __builtin_amdgcn_mfma_f32_32x32x16_bf16(ka, qfA[ds], sA, 0, 0, 0);
        sB = __builtin_amdgcn_mfma_f32_32x32x16_bf16(ka, qfB[ds], sB, 0, 0, 0);
      }
      __builtin_amdgcn_s_setprio(0);

      // p = exp2(s) in place (fixed max; Q pre-scaled to base-2 units)
      if (bits == ~0ull) {
#pragma unroll
        for (int r = 0; r < 16; ++r) { sA[r] = fexp2(sA[r]); sB[r] = fexp2(sB[r]); }
      } else {
#pragma unroll
        for (int r = 0; r < 16; ++r) {
          const int k0 = half * 32 + (r & 3) + 8 * (r >> 2) + 4 * hi;
          const bool on = (bits >> k0) & 1;
          sA[r] = on ? fexp2(sA[r]) : 0.f;
          sB[r] = on ? fexp2(sB[r]) : 0.f;
        }
      }

      // lane-local partial sums (cross-half shfl deferred to epilogue)
      {
        float a0 = 0.f, a1 = 0.f, b0 = 0.f, b1 = 0.f;
#pragma unroll
        for (int r = 0; r < 16; r += 2) {
          a0 += sA[r]; a1 += sA[r + 1];
          b0 += sB[r]; b1 += sB[r + 1];
        }
        lA += a0 + a1;
        lB += b0 + b1;
      }

      short8 pA0, pA1, pB0, pB1;
      PACK(sA, pA0, pA1);
      PACK(sB, pB0, pB1);

      // O^T += V^T * P^T; each va feeds BOTH Q-sets
      __builtin_amdgcn_s_setprio(1);
      {
        const int rb0 = q31 * 128, rb1 = (32 + q31) * 128;
        const int c0 = (half * 64 + kcol) ^ rswz;
        const int c1 = (half * 64 + 32 + kcol) ^ rswz;
        short8 va;
        va = *(const short8*)((const char*)Vs + rb0 + c0);
        oA0 = __builtin_amdgcn_mfma_f32_32x32x16_bf16(va, pA0, oA0, 0, 0, 0);
        oB0 = __builtin_amdgcn_mfma_f32_32x32x16_bf16(va, pB0, oB0, 0, 0, 0);
        va = *(const short8*)((const char*)Vs + rb0 + c1);
        oA0 = __builtin_amdgcn_mfma_f32_32x32x16_bf16(va, pA1, oA0, 0, 0, 0);
        oB0 = __builtin_amdgcn_mfma_f32_32x32x16_bf16(va, pB1, oB0, 0, 0, 0);
        va = *(const short8*)((const char*)Vs + rb1 + c0);
        oA1 = __builtin_amdgcn_mfma_f32_32x32x16_bf16(va, pA0, oA1, 0, 0, 0);
        oB1 = __builtin_amdgcn_mfma_f32_32x32x16_bf16(va, pB0, oB1, 0, 0, 0);
        va = *(const short8*)((const char*)Vs + rb1 + c1);
        oA1 = __builtin_amdgcn_mfma_f32_32x32x16_bf16(va, pA1, oA1, 0, 0, 0);
        oB1 = __builtin_amdgcn_mfma_f32_32x32x16_bf16(va, pB1, oB1, 0, 0, 0);
      }
      __builtin_amdgcn_s_setprio(0);
    }

    __builtin_amdgcn_sched_barrier(0);
    __builtin_amdgcn_s_barrier();   // all waves done reading this tile's LDS
    __builtin_amdgcn_sched_barrier(0);
    mk = mk_next;
  }
#undef LOADT

  // epilogue: finish l sums (one cross-half shfl each), normalize, store
  lA += __shfl_xor(lA, 32);
  lB += __shfl_xor(lB, 32);
  const float invA = lA > 0.f ? 1.f / lA : 0.f;
  const float invB = lB > 0.f ? 1.f / lB : 0.f;
  const int tokA = q0 + q31;
  u16* crowA = ctx + ((size_t)b_ * 2048 + tokA) * 1024 + h_ * 64 + 4 * hi;
  u16* crowB = crowA + 32 * 1024;
#pragma unroll
  for (int g = 0; g < 4; ++g) {
    unsigned u0, u1;
    u0 = cvtpk(oA0[4 * g + 0] * invA, oA0[4 * g + 1] * invA);
    u1 = cvtpk(oA0[4 * g + 2] * invA, oA0[4 * g + 3] * invA);
    *(uint2*)(crowA + 8 * g) = make_uint2(u0, u1);
    u0 = cvtpk(oA1[4 * g + 0] * invA, oA1[4 * g + 1] * invA);
    u1 = cvtpk(oA1[4 * g + 2] * invA, oA1[4 * g + 3] * invA);
    *(uint2*)(crowA + 32 + 8 * g) = make_uint2(u0, u1);
    u0 = cvtpk(oB0[4 * g + 0] * invB, oB0[4 * g + 1] * invB);
    u1 = cvtpk(oB0[4 * g + 2] * invB, oB0[4 * g + 3] * invB);
    *(uint2*)(crowB + 8 * g) = make_uint2(u0, u1);
    u0 = cvtpk(oB1[4 * g + 0] * invB, oB1[4 * g + 1] * invB);
    u1 = cvtpk(oB1[4 * g + 2] * invB, oB1[4 * g + 3] * invB);
    *(uint2*)(crowB + 32 + 8 * g) = make_uint2(u0, u1);
  }
}

// ---------------- host launcher ----------------
extern "C" void kernel_launch(void* const* d_in, const int* in_sizes, int n_in,
                              void* d_out, int out_size, void* d_ws, size_t ws_size,
                              hipStream_t stream) {
  const float* q_in = (const float*)d_in[0];
  const float* k_in = (const float*)d_in[1];
  const float* v_in = (const float*)d_in[2];
  const int*   mask = (const int*)d_in[3];
  const float* Wq = (const float*)d_in[4];
  const float* bq = (const float*)d_in[5];
  const float* Wk = (const float*)d_in[6];
  const float* bk = (const float*)d_in[7];
  const float* Wv = (const float*)d_in[8];
  const float* bv = (const float*)d_in[9];
  const float* Wo = (const float*)d_in[10];
  const float* bo = (const float*)d_in[11];
  float* out = (float*)d_out;

  char* ws = (char*)d_ws;
  u16* xq = (u16*)(ws);                        // bf16 query  [B,T,F]
  u16* xk = (u16*)(ws + 16777216);             // bf16 key
  u16* xv = (u16*)(ws + 33554432);             // bf16 value
  u16* Qp = (u16*)(ws + 50331648);             // [B,h,T,dk], pre-scaled
  u16* Kp = (u16*)(ws + 67108864);             // [B,h,T,dk]
  u16* Vtb = (u16*)(ws + 83886080);            // [B,h,dk,T]
  u16* wqb = (u16*)(ws + 100663296);           // bf16 weights, 2 MiB each
  u16* wkb = (u16*)(ws + 102760448);
  u16* wvb = (u16*)(ws + 104857600);
  u16* wob = (u16*)(ws + 106954752);
  u16* ctx = xk;  // [B,T,F] (key bf16 dead after K projection)

  // converts: 3 big tensors (2^21 float4 each), 4 weights (2^18 float4 each)
  CvtArgs big;
  big.src[0] = q_in; big.src[1] = k_in; big.src[2] = v_in; big.src[3] = v_in;
  big.dst[0] = xq;   big.dst[1] = xk;   big.dst[2] = xv;   big.dst[3] = xv;
  cvt_multi<<<3 * 8192, 256, 0, stream>>>(big, 21);
  CvtArgs wts;
  wts.src[0] = Wq;  wts.src[1] = Wk;  wts.src[2] = Wv;  wts.src[3] = Wo;
  wts.dst[0] = wqb; wts.dst[1] = wkb; wts.dst[2] = wvb; wts.dst[3] = wob;
  cvt_multi<<<4 * 1024, 256, 0, stream>>>(wts, 18);

  const float C_SCALE = 0.18033688011112042f;  // (1/sqrt(64)) * log2(e)
  gemm_bt<0><<<512, 256, 0, stream>>>(xq, wqb, bq, Qp, C_SCALE);
  gemm_bt<0><<<512, 256, 0, stream>>>(xk, wkb, bk, Kp, 1.0f);
  gemm_bt<2><<<512, 256, 0, stream>>>(xv, wvb, bv, Vtb, 1.0f);

  attn_fwd7<<<512, 256, 0, stream>>>(Qp, Kp, Vtb, mask, ctx);

  gemm_bt<1><<<512, 256, 0, stream>>>(ctx, wob, bo, out, 1.0f);
}

// Round 9
// 215.103 us; speedup vs baseline: 3.8484x; 1.1165x over previous
//
#include <hip/hip_runtime.h>
#include <hip/hip_bf16.h>

// MultiHeadedAttention: B=4, T=2048, F=1024, h=16, dk=64.
// proj GEMMs read f32 inputs directly (fused convert in A-staging; Q pre-scaled,
// V written transposed) -> flash attn v5 (R6, 2 Q-sets/wave) -> out GEMM (bf16 A).

typedef unsigned short u16;
typedef unsigned long long u64;
typedef __attribute__((ext_vector_type(8))) short short8;
typedef __attribute__((ext_vector_type(4))) float f32x4;
typedef __attribute__((ext_vector_type(16))) float f32x16;
typedef __attribute__((ext_vector_type(4))) unsigned int u32x4;

#define GLOAD16(g, l) __builtin_amdgcn_global_load_lds( \
    (const __attribute__((address_space(1))) unsigned int*)(g), \
    (__attribute__((address_space(3))) unsigned int*)(l), 16, 0, 0)

__device__ __forceinline__ u16 f2bf(float x) {
  unsigned int u = __float_as_uint(x);
  return (u16)((u + 0x7fffu + ((u >> 16) & 1u)) >> 16);  // RNE, finite inputs
}

__device__ __forceinline__ float fexp2(float x) {
#if __has_builtin(__builtin_amdgcn_exp2f)
  return __builtin_amdgcn_exp2f(x);
#else
  return exp2f(x);
#endif
}

__device__ __forceinline__ unsigned cvtpk(float lo, float hi) {
  unsigned r;
  asm("v_cvt_pk_bf16_f32 %0, %1, %2" : "=v"(r) : "v"(lo), "v"(hi));
  return r;
}

// ---------------- f32 -> bf16 multi-tensor convert (weights only now) ----------------
struct CvtArgs {
  const float* src[4];
  u16* dst[4];
};

__global__ __launch_bounds__(256) void cvt_multi(CvtArgs a, int shift) {
  const int id = blockIdx.x * 256 + threadIdx.x;
  const int seg = id >> shift;
  const int off = id & ((1 << shift) - 1);
  float4 v = ((const float4*)a.src[seg])[off];
  ushort4 o;
  o.x = f2bf(v.x); o.y = f2bf(v.y); o.z = f2bf(v.z); o.w = f2bf(v.w);
  ((ushort4*)a.dst[seg])[off] = o;
}

// ---------------- GEMM: C[M,N] = A[M,K] * B[N,K]^T + bias ----------------
// M=8192, N=K=1024. 128x128 tile, BK=64, 256 threads (4 waves, 2x2).
// AF32=1: A is f32 in global; staged raw via global_load_lds into f32 LDS
//         (granule-XOR swizzle with r&15), converted to bf16 at fragment read.
// EPI 0: bf16 out scattered to [B,h,T,dk], scaled.  EPI 1: f32 out [M,N].
// EPI 2: bf16 out scattered to [B,h,dk,T] (transposed V).
template <int EPI, int AF32>
__global__ __launch_bounds__(256) void gemm_bt(const void* __restrict__ Ap,
                                               const u16* __restrict__ Bw,
                                               const float* __restrict__ bias,
                                               void* __restrict__ Cout,
                                               float scale) {
  __shared__ __align__(16) char As[AF32 ? 32768 : 16384];
  __shared__ __align__(16) char Bs[16384];
  const int t = threadIdx.x;
  const int lane = t & 63;
  const int w = t >> 6;
  const int wm = w >> 1, wn = w & 1;
  const int l15 = lane & 15, l4 = lane >> 4;

  const int bid = blockIdx.x;
  const int swz = (bid & 7) * 64 + (bid >> 3);
  const int brow = swz >> 3;  // 64 M-tiles
  const int bcol = swz & 7;   // 8 N-tiles

  f32x4 acc[4][4] = {};

  const int srow = t >> 3;          // 0..31   (bf16 staging)
  const int sbyte = (t & 7) * 16;   // 0..112
  const int srowA = t >> 4;         // 0..15   (f32 staging)
  const int sbyteA = (t & 15) * 16; // 0..240

  for (int kt = 0; kt < 16; ++kt) {
    const int k0 = kt * 64;
    __syncthreads();
    if constexpr (AF32) {
      const float* A = (const float*)Ap;
#pragma unroll
      for (int i = 0; i < 8; ++i) {
        const int r = i * 16 + srowA;
        const int sb = sbyteA ^ ((r & 15) << 4);
        GLOAD16((const char*)(A + (size_t)(brow * 128 + r) * 1024 + k0) + sb,
                As + i * 4096 + t * 16);
      }
    } else {
      const u16* A = (const u16*)Ap;
#pragma unroll
      for (int i = 0; i < 4; ++i) {
        const int r = i * 32 + srow;
        const int sb = sbyte ^ ((r & 7) << 4);
        GLOAD16((const char*)(A + (size_t)(brow * 128 + r) * 1024 + k0) + sb,
                As + i * 4096 + t * 16);
      }
    }
#pragma unroll
    for (int i = 0; i < 4; ++i) {
      const int r = i * 32 + srow;
      const int sb = sbyte ^ ((r & 7) << 4);
      GLOAD16((const char*)(Bw + (size_t)(bcol * 128 + r) * 1024 + k0) + sb,
              Bs + i * 4096 + t * 16);
    }
    __syncthreads();
#pragma unroll
    for (int kf = 0; kf < 2; ++kf) {
      short8 af[4], bfv[4];
#pragma unroll
      for (int mi = 0; mi < 4; ++mi) {
        const int r = wm * 64 + mi * 16 + l15;
        if constexpr (AF32) {
          const int base = r * 256;
          const int cb = kf * 128 + l4 * 32;   // f32 bytes (elem kf*32 + l4*8)
          const int m0 = (r & 15) << 4;
          float4 x = *(const float4*)(As + base + ((cb) ^ m0));
          float4 y = *(const float4*)(As + base + ((cb + 16) ^ m0));
          u32x4 p = {cvtpk(x.x, x.y), cvtpk(x.z, x.w),
                     cvtpk(y.x, y.y), cvtpk(y.z, y.w)};
          af[mi] = __builtin_bit_cast(short8, p);
        } else {
          const int byt = r * 128 + ((kf * 64 + l4 * 16) ^ ((r & 7) << 4));
          af[mi] = *(const short8*)(As + byt);
        }
      }
#pragma unroll
      for (int ni = 0; ni < 4; ++ni) {
        const int r = wn * 64 + ni * 16 + l15;
        const int byt = r * 128 + ((kf * 64 + l4 * 16) ^ ((r & 7) << 4));
        bfv[ni] = *(const short8*)(Bs + byt);
      }
#pragma unroll
      for (int mi = 0; mi < 4; ++mi)
#pragma unroll
        for (int ni = 0; ni < 4; ++ni)
          acc[mi][ni] = __builtin_amdgcn_mfma_f32_16x16x32_bf16(
              af[mi], bfv[ni], acc[mi][ni], 0, 0, 0);
    }
  }

#pragma unroll
  for (int ni = 0; ni < 4; ++ni) {
    const int n = bcol * 128 + wn * 64 + ni * 16 + l15;
    const float bn = bias[n];
#pragma unroll
    for (int mi = 0; mi < 4; ++mi) {
      const int mb = brow * 128 + wm * 64 + mi * 16 + l4 * 4;
#pragma unroll
      for (int r = 0; r < 4; ++r) {
        const float v = acc[mi][ni][r] + bn;
        const int m = mb + r;
        const int b_ = m >> 11, tok = m & 2047, h_ = n >> 6, d = n & 63;
        if (EPI == 0) {
          ((u16*)Cout)[(((size_t)(b_ * 16 + h_) * 2048 + tok) << 6) + d] = f2bf(v * scale);
        } else if (EPI == 2) {
          ((u16*)Cout)[(((size_t)(b_ * 16 + h_) * 64 + d) << 11) + tok] = f2bf(v);
        } else {
          ((float*)Cout)[(size_t)m * 1024 + n] = v;
        }
      }
    }
  }
}

// ---------------- Flash attention v5 (R6, best measured: 111.9 us) ----------------
// Grid: 64 heads * 8 q-tiles = 512 blocks, 256 threads (4 waves x 64 Q-rows).
// Each LDS K/V A-fragment feeds TWO MFMAs (Q-set A and B).
// Fixed-max softmax (Q pre-scaled to base-2); l summed lane-locally, one shfl at end.
__global__ __launch_bounds__(256, 2) void attn_fwd5(const u16* __restrict__ Q,
                                                    const u16* __restrict__ Kp,
                                                    const u16* __restrict__ Vt,
                                                    const int* __restrict__ mask,
                                                    u16* __restrict__ ctx) {
  __shared__ u16 Ks[2][64 * 64];
  __shared__ u16 Vs[2][64 * 64];

  const int t = threadIdx.x, lane = t & 63, w = t >> 6;
  const int q31 = lane & 31, hi = lane >> 5;

  const int bid = blockIdx.x;                 // 512 blocks, 512%8==0
  const int swz = (bid & 7) * 64 + (bid >> 3);
  const int bh = swz >> 3;                    // 0..63
  const int b_ = bh >> 4, h_ = bh & 15;
  const int q0 = (swz & 7) * 256 + w * 64;    // wave owns 64 queries
  const size_t headO = (size_t)bh * 131072;   // 2048*64

  short8 qfA[4], qfB[4];
  {
    const u16* qrowA = Q + headO + (size_t)(q0 + q31) * 64 + hi * 8;
    const u16* qrowB = qrowA + 32 * 64;
#pragma unroll
    for (int ds = 0; ds < 4; ++ds) {
      qfA[ds] = *(const short8*)(qrowA + ds * 16);
      qfB[ds] = *(const short8*)(qrowB + ds * 16);
    }
  }

  const int srow = t >> 3;          // 0..31
  const int sbyte = (t & 7) * 16;   // 0..112

#define STAGE_KV(bufi, kb)                                                      \
  {                                                                             \
    _Pragma("unroll") for (int i = 0; i < 2; ++i) {                             \
      const int r = i * 32 + srow;                                              \
      const int sb = sbyte ^ ((r & 7) << 4);                                    \
      GLOAD16((const char*)(Kp + headO + (size_t)((kb) + r) * 64) + sb,         \
              &Ks[bufi][(i * 4096 + t * 16) >> 1]);                             \
      GLOAD16((const char*)(Vt + headO + (size_t)r * 2048 + (kb)) + sb,         \
              &Vs[bufi][(i * 4096 + t * 16) >> 1]);                             \
    }                                                                           \
  }

#define PACK(sv, pfa, pfb)                                                      \
  {                                                                             \
    const unsigned w0 = cvtpk(sv[0], sv[1]),   w1 = cvtpk(sv[2], sv[3]);        \
    const unsigned w2 = cvtpk(sv[4], sv[5]),   w3 = cvtpk(sv[6], sv[7]);        \
    const unsigned w4 = cvtpk(sv[8], sv[9]),   w5 = cvtpk(sv[10], sv[11]);      \
    const unsigned w6 = cvtpk(sv[12], sv[13]), w7 = cvtpk(sv[14], sv[15]);      \
    const unsigned x0 = (unsigned)__shfl_xor((int)(hi ? w0 : w2), 32);          \
    const unsigned x1 = (unsigned)__shfl_xor((int)(hi ? w1 : w3), 32);          \
    const unsigned y0 = (unsigned)__shfl_xor((int)(hi ? w4 : w6), 32);          \
    const unsigned y1 = (unsigned)__shfl_xor((int)(hi ? w5 : w7), 32);          \
    u32x4 fa = hi ? (u32x4){x0, x1, w2, w3} : (u32x4){w0, w1, x0, x1};          \
    u32x4 fb = hi ? (u32x4){y0, y1, w6, w7} : (u32x4){w4, w5, y0, y1};          \
    pfa = __builtin_bit_cast(short8, fa);                                       \
    pfb = __builtin_bit_cast(short8, fb);                                       \
  }

  f32x16 oA0 = {}, oA1 = {}, oB0 = {}, oB1 = {};
  float lA = 0.f, lB = 0.f;
  const int kcol = hi * 16;
  const int rswz = (q31 & 7) << 4;

  STAGE_KV(0, 0);
  int mk = mask[b_ * 2048 + lane];
  __syncthreads();

  int buf = 0;
  for (int kt = 0; kt < 32; ++kt) {
    const int kb = kt * 64;
    if (kt + 1 < 32) STAGE_KV(buf ^ 1, kb + 64);
    const int mk_next = (kt + 1 < 32) ? mask[b_ * 2048 + kb + 64 + lane] : 0;
    const u64 bits = __ballot(mk != 0);

#pragma unroll
    for (int half = 0; half < 2; ++half) {
      f32x16 sA = {}, sB = {};
      __builtin_amdgcn_s_setprio(1);
#pragma unroll
      for (int ds = 0; ds < 4; ++ds) {
        const int byt = (half * 32 + q31) * 128 + ((ds * 32 + kcol) ^ rswz);
        short8 ka = *(const short8*)&Ks[buf][byt >> 1];
        sA = __builtin_amdgcn_mfma_f32_32x32x16_bf16(ka, qfA[ds], sA, 0, 0, 0);
        sB = __builtin_amdgcn_mfma_f32_32x32x16_bf16(ka, qfB[ds], sB, 0, 0, 0);
      }
      __builtin_amdgcn_s_setprio(0);

      if (bits == ~0ull) {
#pragma unroll
        for (int r = 0; r < 16; ++r) { sA[r] = fexp2(sA[r]); sB[r] = fexp2(sB[r]); }
      } else {
#pragma unroll
        for (int r = 0; r < 16; ++r) {
          const int k0 = half * 32 + (r & 3) + 8 * (r >> 2) + 4 * hi;
          const bool on = (bits >> k0) & 1;
          sA[r] = on ? fexp2(sA[r]) : 0.f;
          sB[r] = on ? fexp2(sB[r]) : 0.f;
        }
      }

      {
        float a0 = 0.f, a1 = 0.f, b0 = 0.f, b1 = 0.f;
#pragma unroll
        for (int r = 0; r < 16; r += 2) {
          a0 += sA[r]; a1 += sA[r + 1];
          b0 += sB[r]; b1 += sB[r + 1];
        }
        lA += a0 + a1;
        lB += b0 + b1;
      }

      short8 pA0, pA1, pB0, pB1;
      PACK(sA, pA0, pA1);
      PACK(sB, pB0, pB1);

      __builtin_amdgcn_s_setprio(1);
      {
        const int rb0 = q31 * 128, rb1 = (32 + q31) * 128;
        const int c0 = (half * 64 + kcol) ^ rswz;
        const int c1 = (half * 64 + 32 + kcol) ^ rswz;
        short8 va;
        va = *(const short8*)&Vs[buf][(rb0 + c0) >> 1];
        oA0 = __builtin_amdgcn_mfma_f32_32x32x16_bf16(va, pA0, oA0, 0, 0, 0);
        oB0 = __builtin_amdgcn_mfma_f32_32x32x16_bf16(va, pB0, oB0, 0, 0, 0);
        va = *(const short8*)&Vs[buf][(rb0 + c1) >> 1];
        oA0 = __builtin_amdgcn_mfma_f32_32x32x16_bf16(va, pA1, oA0, 0, 0, 0);
        oB0 = __builtin_amdgcn_mfma_f32_32x32x16_bf16(va, pB1, oB0, 0, 0, 0);
        va = *(const short8*)&Vs[buf][(rb1 + c0) >> 1];
        oA1 = __builtin_amdgcn_mfma_f32_32x32x16_bf16(va, pA0, oA1, 0, 0, 0);
        oB1 = __builtin_amdgcn_mfma_f32_32x32x16_bf16(va, pB0, oB1, 0, 0, 0);
        va = *(const short8*)&Vs[buf][(rb1 + c1) >> 1];
        oA1 = __builtin_amdgcn_mfma_f32_32x32x16_bf16(va, pA1, oA1, 0, 0, 0);
        oB1 = __builtin_amdgcn_mfma_f32_32x32x16_bf16(va, pB1, oB1, 0, 0, 0);
      }
      __builtin_amdgcn_s_setprio(0);
    }

    mk = mk_next;
    __syncthreads();
    buf ^= 1;
  }
#undef STAGE_KV

  lA += __shfl_xor(lA, 32);
  lB += __shfl_xor(lB, 32);
  const float invA = lA > 0.f ? 1.f / lA : 0.f;
  const float invB = lB > 0.f ? 1.f / lB : 0.f;
  const int tokA = q0 + q31;
  u16* crowA = ctx + ((size_t)b_ * 2048 + tokA) * 1024 + h_ * 64 + 4 * hi;
  u16* crowB = crowA + 32 * 1024;
#pragma unroll
  for (int g = 0; g < 4; ++g) {
    unsigned u0, u1;
    u0 = cvtpk(oA0[4 * g + 0] * invA, oA0[4 * g + 1] * invA);
    u1 = cvtpk(oA0[4 * g + 2] * invA, oA0[4 * g + 3] * invA);
    *(uint2*)(crowA + 8 * g) = make_uint2(u0, u1);
    u0 = cvtpk(oA1[4 * g + 0] * invA, oA1[4 * g + 1] * invA);
    u1 = cvtpk(oA1[4 * g + 2] * invA, oA1[4 * g + 3] * invA);
    *(uint2*)(crowA + 32 + 8 * g) = make_uint2(u0, u1);
    u0 = cvtpk(oB0[4 * g + 0] * invB, oB0[4 * g + 1] * invB);
    u1 = cvtpk(oB0[4 * g + 2] * invB, oB0[4 * g + 3] * invB);
    *(uint2*)(crowB + 8 * g) = make_uint2(u0, u1);
    u0 = cvtpk(oB1[4 * g + 0] * invB, oB1[4 * g + 1] * invB);
    u1 = cvtpk(oB1[4 * g + 2] * invB, oB1[4 * g + 3] * invB);
    *(uint2*)(crowB + 32 + 8 * g) = make_uint2(u0, u1);
  }
}

// ---------------- host launcher ----------------
extern "C" void kernel_launch(void* const* d_in, const int* in_sizes, int n_in,
                              void* d_out, int out_size, void* d_ws, size_t ws_size,
                              hipStream_t stream) {
  const float* q_in = (const float*)d_in[0];
  const float* k_in = (const float*)d_in[1];
  const float* v_in = (const float*)d_in[2];
  const int*   mask = (const int*)d_in[3];
  const float* Wq = (const float*)d_in[4];
  const float* bq = (const float*)d_in[5];
  const float* Wk = (const float*)d_in[6];
  const float* bk = (const float*)d_in[7];
  const float* Wv = (const float*)d_in[8];
  const float* bv = (const float*)d_in[9];
  const float* Wo = (const float*)d_in[10];
  const float* bo = (const float*)d_in[11];
  float* out = (float*)d_out;

  char* ws = (char*)d_ws;
  u16* ctx = (u16*)(ws);                       // [B,T,F] bf16 attn output
  u16* Qp = (u16*)(ws + 50331648);             // [B,h,T,dk], pre-scaled
  u16* Kp = (u16*)(ws + 67108864);             // [B,h,T,dk]
  u16* Vtb = (u16*)(ws + 83886080);            // [B,h,dk,T]
  u16* wqb = (u16*)(ws + 100663296);           // bf16 weights, 2 MiB each
  u16* wkb = (u16*)(ws + 102760448);
  u16* wvb = (u16*)(ws + 104857600);
  u16* wob = (u16*)(ws + 106954752);

  // weights f32 -> bf16 (4 x 2^18 float4)
  CvtArgs wts;
  wts.src[0] = Wq;  wts.src[1] = Wk;  wts.src[2] = Wv;  wts.src[3] = Wo;
  wts.dst[0] = wqb; wts.dst[1] = wkb; wts.dst[2] = wvb; wts.dst[3] = wob;
  cvt_multi<<<4 * 1024, 256, 0, stream>>>(wts, 18);

  const float C_SCALE = 0.18033688011112042f;  // (1/sqrt(64)) * log2(e)
  // projections read f32 inputs directly (fused convert in A-staging)
  gemm_bt<0, 1><<<512, 256, 0, stream>>>(q_in, wqb, bq, Qp, C_SCALE);
  gemm_bt<0, 1><<<512, 256, 0, stream>>>(k_in, wkb, bk, Kp, 1.0f);
  gemm_bt<2, 1><<<512, 256, 0, stream>>>(v_in, wvb, bv, Vtb, 1.0f);

  attn_fwd5<<<512, 256, 0, stream>>>(Qp, Kp, Vtb, mask, ctx);

  // output projection (bf16 A path)
  gemm_bt<1, 0><<<512, 256, 0, stream>>>(ctx, wob, bo, out, 1.0f);
}